// Round 13
// baseline (332.048 us; speedup 1.0000x reference)
//
#include <hip/hip_runtime.h>
#include <hip/hip_fp16.h>

#define N_NODES 100000
#define N_EDGES 1600000
#define HID 64

#define BSH 8                         // bucket = dst >> 8 (256 nodes per bucket)
#define NBKT ((N_NODES + 255) / 256)  // 391
#define CAP 6144                      // fixed tmp region per bucket (mean 4093, sd 64)
#define TILE 8192                     // edges per bucket_kernel block (ed[] = 64 KB LDS)

// Pass A: bin edges by dst-bucket into fixed-capacity bucket regions of tmp.
// bcur is a zero-initialized per-bucket counter (region base = b*CAP).
// packed tmp word: (dst & 255) << 17 | src   (src < 2^17)
__global__ void __launch_bounds__(512) bucket_kernel(const int* __restrict__ src,
                                                     const int* __restrict__ dst,
                                                     int* __restrict__ bcur,
                                                     unsigned int* __restrict__ tmp) {
    __shared__ unsigned long long ed[TILE];  // 64 KB staged (dst<<32 | src)
    __shared__ int cnt[NBKT], cnt2[NBKT], scnx[NBKT], gbase[NBKT];
    __shared__ int s[512];
    int tid = threadIdx.x;
    int bstart = blockIdx.x * TILE;
    int tcnt = N_EDGES - bstart;
    if (tcnt > TILE) tcnt = TILE;
    if (tcnt < 0) tcnt = 0;
    for (int b = tid; b < NBKT; b += 512) { cnt[b] = 0; cnt2[b] = 0; }
    __syncthreads();
    for (int i = tid; i < tcnt; i += 512) atomicAdd(&cnt[dst[bstart + i] >> BSH], 1);
    __syncthreads();
    s[tid] = (tid < NBKT) ? cnt[tid] : 0;
    __syncthreads();
    for (int off = 1; off < 512; off <<= 1) {
        int add = (tid >= off) ? s[tid - off] : 0;
        __syncthreads();
        s[tid] += add;
        __syncthreads();
    }
    if (tid < NBKT) {
        scnx[tid] = s[tid] - cnt[tid];
        gbase[tid] = tid * CAP + atomicAdd(&bcur[tid], cnt[tid]);
    }
    __syncthreads();
    for (int i = tid; i < tcnt; i += 512) {
        int e = bstart + i;
        int d = dst[e], sc = src[e];
        int b = d >> BSH;
        int pos = scnx[b] + atomicAdd(&cnt2[b], 1);
        ed[pos] = ((unsigned long long)(unsigned)d << 32) | (unsigned)sc;
    }
    __syncthreads();
    for (int i = tid; i < tcnt; i += 512) {
        unsigned long long v = ed[i];
        int d = (int)(v >> 32);
        unsigned sc = (unsigned)v;
        int b = d >> BSH;
        int idx = gbase[b] + (i - scnx[b]);
        if (idx < (b + 1) * CAP)  // statistically unreachable guard
            tmp[idx] = ((unsigned)(d & 255) << 17) | sc;
    }
}

// Scan of per-bucket counts -> global bucket offsets; rowp[N]=total.
__global__ void __launch_bounds__(512) kscan_bkt(const int* __restrict__ bcur,
                                                 int* __restrict__ bkt_off,
                                                 int* __restrict__ rowp) {
    __shared__ int s[512];
    int t = threadIdx.x;
    int v = 0;
    if (t < NBKT) {
        v = bcur[t];
        if (v > CAP) v = CAP;
    }
    s[t] = v;
    __syncthreads();
    for (int off = 1; off < 512; off <<= 1) {
        int a = (t >= off) ? s[t - off] : 0;
        __syncthreads();
        s[t] += a;
        __syncthreads();
    }
    if (t < NBKT) bkt_off[t] = s[t] - v;
    if (t == 511) { bkt_off[NBKT] = s[511]; rowp[N_NODES] = s[511]; }
}

// Pass B: per bucket -- node degrees in LDS, scan -> rowp, counting-sort scatter.
__global__ void __launch_bounds__(256) passb_kernel(const unsigned int* __restrict__ tmp,
                                                    const int* __restrict__ bkt_off,
                                                    int* __restrict__ rowp,
                                                    int* __restrict__ ssrc) {
    __shared__ int cnt[256], s[256], cur[256];
    int tid = threadIdx.x;
    int b = blockIdx.x;
    int lo_t = b * CAP;
    int ne = bkt_off[b + 1] - bkt_off[b];
    cnt[tid] = 0;
    __syncthreads();
    for (int i = tid; i < ne; i += 256) atomicAdd(&cnt[tmp[lo_t + i] >> 17], 1);
    __syncthreads();
    int v = cnt[tid];
    s[tid] = v;
    __syncthreads();
    for (int off = 1; off < 256; off <<= 1) {
        int a = (tid >= off) ? s[tid - off] : 0;
        __syncthreads();
        s[tid] += a;
        __syncthreads();
    }
    int excl = bkt_off[b] + s[tid] - v;
    int node = (b << BSH) + tid;
    if (node < N_NODES) rowp[node] = excl;
    cur[tid] = excl;
    __syncthreads();
    for (int i = tid; i < ne; i += 256) {
        unsigned u = tmp[lo_t + i];
        int pos = atomicAdd(&cur[u >> 17], 1);
        ssrc[pos] = (int)(u & 0x1FFFF);
    }
}

// Register-tiled dual GEMM: m = fp16(mscale * (h @ relW.T)), aout = h @ rootW.T + relb (fp32).
// mscale is a power of 2 (exact): keeps layer 1-2 m within fp16 range.
// Block tile: 128 nodes x 128 outputs (j<64 -> m, j>=64 -> aout).
// PRE=1: input is x[N,3] fp32; h tile computed in staging as relu(x@preW+preb).
// PRE=0: input is h[N,64] fp32.
// NOTE (R11 bug): xs staging MUST loop t = tid..384 step 256 — a plain
// `if (tid < 384)` with 256 threads leaves xs[256..383] uninitialized LDS,
// which is run-dependent garbage -> nondeterministic output (tripwire).
template <int PRE>
__global__ void __launch_bounds__(256) gemmt_kernel(const float* __restrict__ hx,
                                                    const float* __restrict__ preW,
                                                    const float* __restrict__ preb,
                                                    const float* __restrict__ relW,
                                                    const float* __restrict__ relb,
                                                    const float* __restrict__ rootW,
                                                    float mscale,
                                                    __half* __restrict__ m,
                                                    float* __restrict__ aout) {
    __shared__ float hs[128 * 68];
    __shared__ float ws[128 * 68];
    __shared__ float xs[PRE ? 384 : 1];
    __shared__ float pw[PRE ? 192 : 1];
    __shared__ float pbs[PRE ? 64 : 1];
    int tid = threadIdx.x;
    int i0 = blockIdx.x * 128;
    // stage weights (always)
    for (int c = 0; c < 8; c++) {
        int f = tid + c * 256;  // float4 index over 128x64
        int j = f >> 4, c4 = (f & 15) << 2;
        float4 wv = (j < 64) ? *(const float4*)&relW[j * 64 + c4]
                             : *(const float4*)&rootW[(j - 64) * 64 + c4];
        *(float4*)&ws[j * 68 + c4] = wv;
    }
    if (PRE) {
        if (tid < 192) pw[tid] = preW[tid];
        if (tid < 64) pbs[tid] = preb[tid];
        for (int t = tid; t < 384; t += 256) {  // FULL coverage of xs[0..383]
            int gi = i0 * 3 + t;
            xs[t] = (gi < N_NODES * 3) ? hx[gi] : 0.f;
        }
        __syncthreads();
        for (int c = 0; c < 32; c++) {
            int e = c * 256 + tid;
            int row = e >> 6, col = e & 63;
            float v = pbs[col];
            v = fmaf(xs[row * 3 + 0], pw[col * 3 + 0], v);
            v = fmaf(xs[row * 3 + 1], pw[col * 3 + 1], v);
            v = fmaf(xs[row * 3 + 2], pw[col * 3 + 2], v);
            hs[row * 68 + col] = fmaxf(v, 0.f);
        }
    } else {
        for (int c = 0; c < 8; c++) {
            int f = tid + c * 256;            // float4 index, 2048 total
            int row = f >> 4, c4 = (f & 15) << 2;
            float4 hv = {0.f, 0.f, 0.f, 0.f};
            if (i0 + row < N_NODES) hv = *(const float4*)&hx[(long)(i0 + row) * 64 + c4];
            *(float4*)&hs[row * 68 + c4] = hv;
        }
    }
    int ig = tid >> 4;   // node group 0..15, nodes ig+16n
    int jg = tid & 15;   // out group 0..15,  outs  jg+16m
    float rb[4];
#pragma unroll
    for (int t = 0; t < 4; t++) rb[t] = relb[jg + 16 * t];
    float acc[8][8];
#pragma unroll
    for (int n = 0; n < 8; n++)
#pragma unroll
        for (int mm = 0; mm < 8; mm++) acc[n][mm] = 0.f;
    __syncthreads();

    for (int kk = 0; kk < 64; kk += 4) {
        float4 av[8], bv[8];
#pragma unroll
        for (int n = 0; n < 8; n++) av[n] = *(const float4*)&hs[(ig + 16 * n) * 68 + kk];
#pragma unroll
        for (int mm = 0; mm < 8; mm++) bv[mm] = *(const float4*)&ws[(jg + 16 * mm) * 68 + kk];
#pragma unroll
        for (int n = 0; n < 8; n++)
#pragma unroll
            for (int mm = 0; mm < 8; mm++) {
                acc[n][mm] = fmaf(av[n].x, bv[mm].x, acc[n][mm]);
                acc[n][mm] = fmaf(av[n].y, bv[mm].y, acc[n][mm]);
                acc[n][mm] = fmaf(av[n].z, bv[mm].z, acc[n][mm]);
                acc[n][mm] = fmaf(av[n].w, bv[mm].w, acc[n][mm]);
            }
    }
#pragma unroll
    for (int n = 0; n < 8; n++) {
        int node = i0 + ig + 16 * n;
        if (node >= N_NODES) continue;
#pragma unroll
        for (int mm = 0; mm < 4; mm++)
            m[(long)node * 64 + jg + 16 * mm] = __float2half(acc[n][mm] * mscale);
#pragma unroll
        for (int mm = 4; mm < 8; mm++)
            aout[(long)node * 64 + jg + 16 * (mm - 4)] = acc[n][mm] + rb[mm - 4];
    }
}

// fp16-m gather, 4 nodes per wave: n = lane>>4 (node quarter), g = (lane>>3)&1
// (edge subgroup), f8 = (lane&7)*8 (feature oct). Per-lane direct index loads,
// fp32 accumulate; 8-deep unroll (16 edges in flight per node — mean degree 16
// fits one batch); root-term load hoisted; rowp scalarized.
// aggscale = 1/mscale (power of 2, exact) undoes the fp16 range scaling.
template <int FINAL>
__global__ void gather_kernel(const __half* __restrict__ m, float* __restrict__ a,
                              const int* __restrict__ rowp, const int* __restrict__ ssrc,
                              float aggscale,
                              const float* __restrict__ postW, const float* __restrict__ postb,
                              float* __restrict__ out) {
    int lane = threadIdx.x & 63;
    int wv = (blockIdx.x * blockDim.x + threadIdx.x) >> 6;
    int pb = wv * 4;
    if (pb >= N_NODES) return;
    int n = lane >> 4;          // node quarter 0..3
    int g = (lane >> 3) & 1;    // edge subgroup 0/1
    int f8 = (lane & 7) << 3;   // feature base 0,8,...,56
    pb = __builtin_amdgcn_readfirstlane(pb);
    int q0 = rowp[pb], q1 = rowp[pb + 1], q2 = rowp[pb + 2];
    int q3 = rowp[pb + 3], q4 = rowp[pb + 4];
    int node = pb + n;
    int r0 = (n == 0) ? q0 : (n == 1) ? q1 : (n == 2) ? q2 : q3;
    int r1 = (n == 0) ? q1 : (n == 1) ? q2 : (n == 2) ? q3 : q4;
    int nedge = r1 - r0;
    // hoisted root-term load (overlaps the edge loop)
    const float* arow = a + (long)node * 64 + f8;
    float4 o0 = *(const float4*)arow;
    float4 o1 = *(const float4*)(arow + 4);
    float a0 = 0.f, a1 = 0.f, a2 = 0.f, a3 = 0.f, a4 = 0.f, a5 = 0.f, a6 = 0.f, a7 = 0.f;
#define ACC8(u)                                                         \
    {                                                                   \
        float2 f_;                                                      \
        f_ = __half22float2(*(__half2*)&(u).x); a0 += f_.x; a1 += f_.y; \
        f_ = __half22float2(*(__half2*)&(u).y); a2 += f_.x; a3 += f_.y; \
        f_ = __half22float2(*(__half2*)&(u).z); a4 += f_.x; a5 += f_.y; \
        f_ = __half22float2(*(__half2*)&(u).w); a6 += f_.x; a7 += f_.y; \
    }
    int ns = nedge >> 1;        // pairs of edges (2 subgroups cover 2 edges/iter)
    int q = 0;
    for (; q + 8 <= ns; q += 8) {
        int b0 = r0 + q * 2 + g;
        int i0 = ssrc[b0];
        int i1 = ssrc[b0 + 2];
        int i2 = ssrc[b0 + 4];
        int i3 = ssrc[b0 + 6];
        int i4 = ssrc[b0 + 8];
        int i5 = ssrc[b0 + 10];
        int i6 = ssrc[b0 + 12];
        int i7 = ssrc[b0 + 14];
        uint4 u0 = *(const uint4*)(m + (long)i0 * 64 + f8);
        uint4 u1 = *(const uint4*)(m + (long)i1 * 64 + f8);
        uint4 u2 = *(const uint4*)(m + (long)i2 * 64 + f8);
        uint4 u3 = *(const uint4*)(m + (long)i3 * 64 + f8);
        uint4 u4 = *(const uint4*)(m + (long)i4 * 64 + f8);
        uint4 u5 = *(const uint4*)(m + (long)i5 * 64 + f8);
        uint4 u6 = *(const uint4*)(m + (long)i6 * 64 + f8);
        uint4 u7 = *(const uint4*)(m + (long)i7 * 64 + f8);
        ACC8(u0); ACC8(u1); ACC8(u2); ACC8(u3);
        ACC8(u4); ACC8(u5); ACC8(u6); ACC8(u7);
    }
    if (q + 4 <= ns) {
        int b0 = r0 + q * 2 + g;
        int i0 = ssrc[b0];
        int i1 = ssrc[b0 + 2];
        int i2 = ssrc[b0 + 4];
        int i3 = ssrc[b0 + 6];
        uint4 u0 = *(const uint4*)(m + (long)i0 * 64 + f8);
        uint4 u1 = *(const uint4*)(m + (long)i1 * 64 + f8);
        uint4 u2 = *(const uint4*)(m + (long)i2 * 64 + f8);
        uint4 u3 = *(const uint4*)(m + (long)i3 * 64 + f8);
        ACC8(u0); ACC8(u1); ACC8(u2); ACC8(u3);
        q += 4;
    }
    if (q + 2 <= ns) {
        int b0 = r0 + q * 2 + g;
        int i0 = ssrc[b0];
        int i1 = ssrc[b0 + 2];
        uint4 u0 = *(const uint4*)(m + (long)i0 * 64 + f8);
        uint4 u1 = *(const uint4*)(m + (long)i1 * 64 + f8);
        ACC8(u0); ACC8(u1);
        q += 2;
    }
    if (q < ns) {
        int i0 = ssrc[r0 + q * 2 + g];
        uint4 u0 = *(const uint4*)(m + (long)i0 * 64 + f8);
        ACC8(u0);
    }
    if ((nedge & 1) && g == 0) {
        int i0 = ssrc[r0 + ns * 2];
        uint4 u0 = *(const uint4*)(m + (long)i0 * 64 + f8);
        ACC8(u0);
    }
#undef ACC8
    // reduce across the 2 edge subgroups (stays within each 16-lane node group)
    a0 += __shfl_xor(a0, 8, 64); a1 += __shfl_xor(a1, 8, 64);
    a2 += __shfl_xor(a2, 8, 64); a3 += __shfl_xor(a3, 8, 64);
    a4 += __shfl_xor(a4, 8, 64); a5 += __shfl_xor(a5, 8, 64);
    a6 += __shfl_xor(a6, 8, 64); a7 += __shfl_xor(a7, 8, 64);
    // undo fp16 range scaling (exact power-of-2)
    a0 *= aggscale; a1 *= aggscale; a2 *= aggscale; a3 *= aggscale;
    a4 *= aggscale; a5 *= aggscale; a6 *= aggscale; a7 *= aggscale;
    // add root term (fp32) + relu
    a0 = fmaxf(a0 + o0.x, 0.f); a1 = fmaxf(a1 + o0.y, 0.f);
    a2 = fmaxf(a2 + o0.z, 0.f); a3 = fmaxf(a3 + o0.w, 0.f);
    a4 = fmaxf(a4 + o1.x, 0.f); a5 = fmaxf(a5 + o1.y, 0.f);
    a6 = fmaxf(a6 + o1.z, 0.f); a7 = fmaxf(a7 + o1.w, 0.f);
    if (FINAL) {
        float4 w0 = *(const float4*)(postW + f8);
        float4 w1 = *(const float4*)(postW + f8 + 4);
        float4 w2 = *(const float4*)(postW + 64 + f8);
        float4 w3 = *(const float4*)(postW + 64 + f8 + 4);
        float p0 = a0 * w0.x + a1 * w0.y + a2 * w0.z + a3 * w0.w +
                   a4 * w1.x + a5 * w1.y + a6 * w1.z + a7 * w1.w;
        float p1 = a0 * w2.x + a1 * w2.y + a2 * w2.z + a3 * w2.w +
                   a4 * w3.x + a5 * w3.y + a6 * w3.z + a7 * w3.w;
#pragma unroll
        for (int off = 1; off <= 4; off <<= 1) {
            p0 += __shfl_xor(p0, off, 64);
            p1 += __shfl_xor(p1, off, 64);
        }
        if ((lane & 15) == 0) {
            out[(long)node * 2 + 0] = fmaxf(p0 + postb[0], 0.f);
            out[(long)node * 2 + 1] = fmaxf(p1 + postb[1], 0.f);
        }
    } else {
        if (g == 0) {
            float4 r0v; r0v.x = a0; r0v.y = a1; r0v.z = a2; r0v.w = a3;
            float4 r1v; r1v.x = a4; r1v.y = a5; r1v.z = a6; r1v.w = a7;
            float* dst = a + (long)node * 64 + f8;
            *(float4*)dst = r0v;
            *(float4*)(dst + 4) = r1v;
        }
    }
}

extern "C" void kernel_launch(void* const* d_in, const int* in_sizes, int n_in,
                              void* d_out, int out_size, void* d_ws, size_t ws_size,
                              hipStream_t stream) {
    const float* x = (const float*)d_in[0];
    const int* esrc = (const int*)d_in[1];
    const int* edst = esrc + N_EDGES;
    const float* preW = (const float*)d_in[2];
    const float* preb = (const float*)d_in[3];
    const float* postW = (const float*)d_in[4];
    const float* postb = (const float*)d_in[5];
    const float* relW[3] = {(const float*)d_in[6], (const float*)d_in[9], (const float*)d_in[12]};
    const float* relb[3] = {(const float*)d_in[7], (const float*)d_in[10], (const float*)d_in[13]};
    const float* rootW[3] = {(const float*)d_in[8], (const float*)d_in[11], (const float*)d_in[14]};
    float* out = (float*)d_out;

    const size_t NF = (size_t)N_NODES * HID;
    char* p = (char*)d_ws;
    float* hA = (float*)p; p += NF * 4;
    float* hB = (float*)p; p += NF * 4;
    __half* mB = (__half*)p; p += NF * 2;
    p = (char*)(((size_t)p + 255) & ~(size_t)255);
    int* rowp = (int*)p; p += (size_t)(N_NODES + 1) * 4;
    p = (char*)(((size_t)p + 255) & ~(size_t)255);
    int* ssrc = (int*)p; p += (size_t)N_EDGES * 4;
    int* bkt_off = (int*)p; p += 512 * 4;
    int* bcur = (int*)p; p += 512 * 4;
    // tmp (NBKT*CAP*4 = 9.6 MB) aliases mB (12.8 MB): CSR build finishes
    // before any gemmt writes mB.
    unsigned int* tmp = (unsigned int*)mB;

    // --- build CSR (by dst): fixed-cap bins -> scan -> per-bucket sort ---
    hipMemsetAsync(bcur, 0, 512 * 4, stream);
    bucket_kernel<<<(N_EDGES + TILE - 1) / TILE, 512, 0, stream>>>(esrc, edst, bcur, tmp);
    kscan_bkt<<<1, 512, 0, stream>>>(bcur, bkt_off, rowp);
    passb_kernel<<<NBKT, 256, 0, stream>>>(tmp, bkt_off, rowp, ssrc);

    const int GEMM_BLOCKS = (N_NODES + 127) / 128;      // 782
    const int GATHER_BLOCKS = N_NODES / 16;             // 4 nodes/wave, 4 waves/block

    const float S1 = 1.0f / 64.0f, IS1 = 64.0f;  // layers 1-2 fp16 range scaling

    // layer 0 (pre fused): x -> mB, hB(aout); m values ~O(1), no scaling
    gemmt_kernel<1><<<GEMM_BLOCKS, 256, 0, stream>>>(x, preW, preb, relW[0], relb[0],
                                                     rootW[0], 1.0f, mB, hB);
    gather_kernel<0><<<GATHER_BLOCKS, 256, 0, stream>>>(mB, hB, rowp, ssrc, 1.0f,
                                                        nullptr, nullptr, nullptr);
    // layer 1: hB -> mB, hA(aout)
    gemmt_kernel<0><<<GEMM_BLOCKS, 256, 0, stream>>>(hB, nullptr, nullptr, relW[1], relb[1],
                                                     rootW[1], S1, mB, hA);
    gather_kernel<0><<<GATHER_BLOCKS, 256, 0, stream>>>(mB, hA, rowp, ssrc, IS1,
                                                        nullptr, nullptr, nullptr);
    // layer 2 + post: hA -> out
    gemmt_kernel<0><<<GEMM_BLOCKS, 256, 0, stream>>>(hA, nullptr, nullptr, relW[2], relb[2],
                                                     rootW[2], S1, mB, hB);
    gather_kernel<1><<<GATHER_BLOCKS, 256, 0, stream>>>(mB, hB, rowp, ssrc, IS1,
                                                        postW, postb, out);
}

// Round 14
// 324.037 us; speedup vs baseline: 1.0247x; 1.0247x over previous
//
#include <hip/hip_runtime.h>
#include <hip/hip_fp16.h>

#define N_NODES 100000
#define N_EDGES 1600000
#define HID 64

#define BSH 8                         // bucket = dst >> 8 (256 nodes per bucket)
#define NBKT ((N_NODES + 255) / 256)  // 391
#define CAP 6144                      // fixed tmp region per bucket (mean 4093, sd 64)
#define TILE 4096                     // edges per bucket_kernel block (32 KB LDS — 8192/64KB regressed, R13)

// Pass A: bin edges by dst-bucket into fixed-capacity bucket regions of tmp.
// bcur is a zero-initialized per-bucket counter (region base = b*CAP).
// packed tmp word: (dst & 255) << 17 | src   (src < 2^17)
__global__ void __launch_bounds__(512) bucket_kernel(const int* __restrict__ src,
                                                     const int* __restrict__ dst,
                                                     int* __restrict__ bcur,
                                                     unsigned int* __restrict__ tmp) {
    __shared__ unsigned long long ed[TILE];  // 32 KB staged (dst<<32 | src)
    __shared__ int cnt[NBKT], cnt2[NBKT], scnx[NBKT], gbase[NBKT];
    __shared__ int s[512];
    int tid = threadIdx.x;
    int bstart = blockIdx.x * TILE;
    int tcnt = N_EDGES - bstart;
    if (tcnt > TILE) tcnt = TILE;
    if (tcnt < 0) tcnt = 0;
    for (int b = tid; b < NBKT; b += 512) { cnt[b] = 0; cnt2[b] = 0; }
    __syncthreads();
    for (int i = tid; i < tcnt; i += 512) atomicAdd(&cnt[dst[bstart + i] >> BSH], 1);
    __syncthreads();
    s[tid] = (tid < NBKT) ? cnt[tid] : 0;
    __syncthreads();
    for (int off = 1; off < 512; off <<= 1) {
        int add = (tid >= off) ? s[tid - off] : 0;
        __syncthreads();
        s[tid] += add;
        __syncthreads();
    }
    if (tid < NBKT) {
        scnx[tid] = s[tid] - cnt[tid];
        gbase[tid] = tid * CAP + atomicAdd(&bcur[tid], cnt[tid]);
    }
    __syncthreads();
    for (int i = tid; i < tcnt; i += 512) {
        int e = bstart + i;
        int d = dst[e], sc = src[e];
        int b = d >> BSH;
        int pos = scnx[b] + atomicAdd(&cnt2[b], 1);
        ed[pos] = ((unsigned long long)(unsigned)d << 32) | (unsigned)sc;
    }
    __syncthreads();
    for (int i = tid; i < tcnt; i += 512) {
        unsigned long long v = ed[i];
        int d = (int)(v >> 32);
        unsigned sc = (unsigned)v;
        int b = d >> BSH;
        int idx = gbase[b] + (i - scnx[b]);
        if (idx < (b + 1) * CAP)  // statistically unreachable guard
            tmp[idx] = ((unsigned)(d & 255) << 17) | sc;
    }
}

// Pass B: per bucket. Computes its own global offset lo = sum_{b'<b} cnt[b']
// (replaces the separate kscan_bkt dispatch), then node degrees in LDS,
// scan -> rowp, counting-sort scatter into ssrc.
__global__ void __launch_bounds__(256) passb_kernel(const unsigned int* __restrict__ tmp,
                                                    const int* __restrict__ bcur,
                                                    int* __restrict__ rowp,
                                                    int* __restrict__ ssrc) {
    __shared__ int red[256];
    __shared__ int cnt[256], s[256], cur[256];
    int tid = threadIdx.x;
    int b = blockIdx.x;
    // lo = exclusive prefix of clamped bucket counts at b
    int acc = 0;
    for (int i = tid; i < b; i += 256) {
        int c = bcur[i];
        if (c > CAP) c = CAP;
        acc += c;
    }
    red[tid] = acc;
    __syncthreads();
    for (int off = 128; off >= 1; off >>= 1) {
        if (tid < off) red[tid] += red[tid + off];
        __syncthreads();
    }
    int lo = red[0];
    int ne = bcur[b];
    if (ne > CAP) ne = CAP;
    if (b == NBKT - 1 && tid == 0) rowp[N_NODES] = lo + ne;
    int lo_t = b * CAP;
    cnt[tid] = 0;
    __syncthreads();
    for (int i = tid; i < ne; i += 256) atomicAdd(&cnt[tmp[lo_t + i] >> 17], 1);
    __syncthreads();
    int v = cnt[tid];
    s[tid] = v;
    __syncthreads();
    for (int off = 1; off < 256; off <<= 1) {
        int a = (tid >= off) ? s[tid - off] : 0;
        __syncthreads();
        s[tid] += a;
        __syncthreads();
    }
    int excl = lo + s[tid] - v;
    int node = (b << BSH) + tid;
    if (node < N_NODES) rowp[node] = excl;
    cur[tid] = excl;
    __syncthreads();
    for (int i = tid; i < ne; i += 256) {
        unsigned u = tmp[lo_t + i];
        int pos = atomicAdd(&cur[u >> 17], 1);
        ssrc[pos] = (int)(u & 0x1FFFF);
    }
}

// Register-tiled dual GEMM: m = fp16(mscale * (h @ relW.T)), aout = h @ rootW.T + relb (fp32).
// mscale is a power of 2 (exact): keeps layer 1-2 m within fp16 range.
// Block tile: 128 nodes x 128 outputs (j<64 -> m, j>=64 -> aout).
// PRE=1: input is x[N,3] fp32; h tile computed in staging as relu(x@preW+preb).
// PRE=0: input is h[N,64] fp32.
// NOTE (R11 bug): xs staging MUST loop t = tid..384 step 256 — a plain
// `if (tid < 384)` with 256 threads leaves xs[256..383] uninitialized LDS,
// which is run-dependent garbage -> nondeterministic output (tripwire).
template <int PRE>
__global__ void __launch_bounds__(256) gemmt_kernel(const float* __restrict__ hx,
                                                    const float* __restrict__ preW,
                                                    const float* __restrict__ preb,
                                                    const float* __restrict__ relW,
                                                    const float* __restrict__ relb,
                                                    const float* __restrict__ rootW,
                                                    float mscale,
                                                    __half* __restrict__ m,
                                                    float* __restrict__ aout) {
    __shared__ float hs[128 * 68];
    __shared__ float ws[128 * 68];
    __shared__ float xs[PRE ? 384 : 1];
    __shared__ float pw[PRE ? 192 : 1];
    __shared__ float pbs[PRE ? 64 : 1];
    int tid = threadIdx.x;
    int i0 = blockIdx.x * 128;
    // stage weights (always)
    for (int c = 0; c < 8; c++) {
        int f = tid + c * 256;  // float4 index over 128x64
        int j = f >> 4, c4 = (f & 15) << 2;
        float4 wv = (j < 64) ? *(const float4*)&relW[j * 64 + c4]
                             : *(const float4*)&rootW[(j - 64) * 64 + c4];
        *(float4*)&ws[j * 68 + c4] = wv;
    }
    if (PRE) {
        if (tid < 192) pw[tid] = preW[tid];
        if (tid < 64) pbs[tid] = preb[tid];
        for (int t = tid; t < 384; t += 256) {  // FULL coverage of xs[0..383]
            int gi = i0 * 3 + t;
            xs[t] = (gi < N_NODES * 3) ? hx[gi] : 0.f;
        }
        __syncthreads();
        for (int c = 0; c < 32; c++) {
            int e = c * 256 + tid;
            int row = e >> 6, col = e & 63;
            float v = pbs[col];
            v = fmaf(xs[row * 3 + 0], pw[col * 3 + 0], v);
            v = fmaf(xs[row * 3 + 1], pw[col * 3 + 1], v);
            v = fmaf(xs[row * 3 + 2], pw[col * 3 + 2], v);
            hs[row * 68 + col] = fmaxf(v, 0.f);
        }
    } else {
        for (int c = 0; c < 8; c++) {
            int f = tid + c * 256;            // float4 index, 2048 total
            int row = f >> 4, c4 = (f & 15) << 2;
            float4 hv = {0.f, 0.f, 0.f, 0.f};
            if (i0 + row < N_NODES) hv = *(const float4*)&hx[(long)(i0 + row) * 64 + c4];
            *(float4*)&hs[row * 68 + c4] = hv;
        }
    }
    int ig = tid >> 4;   // node group 0..15, nodes ig+16n
    int jg = tid & 15;   // out group 0..15,  outs  jg+16m
    float rb[4];
#pragma unroll
    for (int t = 0; t < 4; t++) rb[t] = relb[jg + 16 * t];
    float acc[8][8];
#pragma unroll
    for (int n = 0; n < 8; n++)
#pragma unroll
        for (int mm = 0; mm < 8; mm++) acc[n][mm] = 0.f;
    __syncthreads();

    for (int kk = 0; kk < 64; kk += 4) {
        float4 av[8], bv[8];
#pragma unroll
        for (int n = 0; n < 8; n++) av[n] = *(const float4*)&hs[(ig + 16 * n) * 68 + kk];
#pragma unroll
        for (int mm = 0; mm < 8; mm++) bv[mm] = *(const float4*)&ws[(jg + 16 * mm) * 68 + kk];
#pragma unroll
        for (int n = 0; n < 8; n++)
#pragma unroll
            for (int mm = 0; mm < 8; mm++) {
                acc[n][mm] = fmaf(av[n].x, bv[mm].x, acc[n][mm]);
                acc[n][mm] = fmaf(av[n].y, bv[mm].y, acc[n][mm]);
                acc[n][mm] = fmaf(av[n].z, bv[mm].z, acc[n][mm]);
                acc[n][mm] = fmaf(av[n].w, bv[mm].w, acc[n][mm]);
            }
    }
#pragma unroll
    for (int n = 0; n < 8; n++) {
        int node = i0 + ig + 16 * n;
        if (node >= N_NODES) continue;
#pragma unroll
        for (int mm = 0; mm < 4; mm++)
            m[(long)node * 64 + jg + 16 * mm] = __float2half(acc[n][mm] * mscale);
#pragma unroll
        for (int mm = 4; mm < 8; mm++)
            aout[(long)node * 64 + jg + 16 * (mm - 4)] = acc[n][mm] + rb[mm - 4];
    }
}

// fp16-m gather, 4 nodes per wave: n = lane>>4 (node quarter), g = (lane>>3)&1
// (edge subgroup), f8 = (lane&7)*8 (feature oct). Per-lane direct index loads,
// fp32 accumulate; root-term load hoisted; rowp scalarized.
// Max 4-pair unroll: deeper (R13) raised VGPRs and cut occupancy — net loss
// for this latency-bound kernel. Keep VGPR footprint small (32).
// aggscale = 1/mscale (power of 2, exact) undoes the fp16 range scaling.
template <int FINAL>
__global__ void gather_kernel(const __half* __restrict__ m, float* __restrict__ a,
                              const int* __restrict__ rowp, const int* __restrict__ ssrc,
                              float aggscale,
                              const float* __restrict__ postW, const float* __restrict__ postb,
                              float* __restrict__ out) {
    int lane = threadIdx.x & 63;
    int wv = (blockIdx.x * blockDim.x + threadIdx.x) >> 6;
    int pb = wv * 4;
    if (pb >= N_NODES) return;
    int n = lane >> 4;          // node quarter 0..3
    int g = (lane >> 3) & 1;    // edge subgroup 0/1
    int f8 = (lane & 7) << 3;   // feature base 0,8,...,56
    pb = __builtin_amdgcn_readfirstlane(pb);
    int q0 = rowp[pb], q1 = rowp[pb + 1], q2 = rowp[pb + 2];
    int q3 = rowp[pb + 3], q4 = rowp[pb + 4];
    int node = pb + n;
    int r0 = (n == 0) ? q0 : (n == 1) ? q1 : (n == 2) ? q2 : q3;
    int r1 = (n == 0) ? q1 : (n == 1) ? q2 : (n == 2) ? q3 : q4;
    int nedge = r1 - r0;
    // hoisted root-term load (overlaps the edge loop)
    const float* arow = a + (long)node * 64 + f8;
    float4 o0 = *(const float4*)arow;
    float4 o1 = *(const float4*)(arow + 4);
    float a0 = 0.f, a1 = 0.f, a2 = 0.f, a3 = 0.f, a4 = 0.f, a5 = 0.f, a6 = 0.f, a7 = 0.f;
#define ACC8(u)                                                         \
    {                                                                   \
        float2 f_;                                                      \
        f_ = __half22float2(*(__half2*)&(u).x); a0 += f_.x; a1 += f_.y; \
        f_ = __half22float2(*(__half2*)&(u).y); a2 += f_.x; a3 += f_.y; \
        f_ = __half22float2(*(__half2*)&(u).z); a4 += f_.x; a5 += f_.y; \
        f_ = __half22float2(*(__half2*)&(u).w); a6 += f_.x; a7 += f_.y; \
    }
    int ns = nedge >> 1;        // pairs of edges (2 subgroups cover 2 edges/iter)
    int q = 0;
    for (; q + 4 <= ns; q += 4) {
        int b0 = r0 + q * 2 + g;
        int i0 = ssrc[b0];
        int i1 = ssrc[b0 + 2];
        int i2 = ssrc[b0 + 4];
        int i3 = ssrc[b0 + 6];
        uint4 u0 = *(const uint4*)(m + (long)i0 * 64 + f8);
        uint4 u1 = *(const uint4*)(m + (long)i1 * 64 + f8);
        uint4 u2 = *(const uint4*)(m + (long)i2 * 64 + f8);
        uint4 u3 = *(const uint4*)(m + (long)i3 * 64 + f8);
        ACC8(u0); ACC8(u1); ACC8(u2); ACC8(u3);
    }
    if (q + 2 <= ns) {
        int b0 = r0 + q * 2 + g;
        int i0 = ssrc[b0];
        int i1 = ssrc[b0 + 2];
        uint4 u0 = *(const uint4*)(m + (long)i0 * 64 + f8);
        uint4 u1 = *(const uint4*)(m + (long)i1 * 64 + f8);
        ACC8(u0); ACC8(u1);
        q += 2;
    }
    if (q < ns) {
        int i0 = ssrc[r0 + q * 2 + g];
        uint4 u0 = *(const uint4*)(m + (long)i0 * 64 + f8);
        ACC8(u0);
    }
    if ((nedge & 1) && g == 0) {
        int i0 = ssrc[r0 + ns * 2];
        uint4 u0 = *(const uint4*)(m + (long)i0 * 64 + f8);
        ACC8(u0);
    }
#undef ACC8
    // reduce across the 2 edge subgroups (stays within each 16-lane node group)
    a0 += __shfl_xor(a0, 8, 64); a1 += __shfl_xor(a1, 8, 64);
    a2 += __shfl_xor(a2, 8, 64); a3 += __shfl_xor(a3, 8, 64);
    a4 += __shfl_xor(a4, 8, 64); a5 += __shfl_xor(a5, 8, 64);
    a6 += __shfl_xor(a6, 8, 64); a7 += __shfl_xor(a7, 8, 64);
    // undo fp16 range scaling (exact power-of-2)
    a0 *= aggscale; a1 *= aggscale; a2 *= aggscale; a3 *= aggscale;
    a4 *= aggscale; a5 *= aggscale; a6 *= aggscale; a7 *= aggscale;
    // add root term (fp32) + relu
    a0 = fmaxf(a0 + o0.x, 0.f); a1 = fmaxf(a1 + o0.y, 0.f);
    a2 = fmaxf(a2 + o0.z, 0.f); a3 = fmaxf(a3 + o0.w, 0.f);
    a4 = fmaxf(a4 + o1.x, 0.f); a5 = fmaxf(a5 + o1.y, 0.f);
    a6 = fmaxf(a6 + o1.z, 0.f); a7 = fmaxf(a7 + o1.w, 0.f);
    if (FINAL) {
        float4 w0 = *(const float4*)(postW + f8);
        float4 w1 = *(const float4*)(postW + f8 + 4);
        float4 w2 = *(const float4*)(postW + 64 + f8);
        float4 w3 = *(const float4*)(postW + 64 + f8 + 4);
        float p0 = a0 * w0.x + a1 * w0.y + a2 * w0.z + a3 * w0.w +
                   a4 * w1.x + a5 * w1.y + a6 * w1.z + a7 * w1.w;
        float p1 = a0 * w2.x + a1 * w2.y + a2 * w2.z + a3 * w2.w +
                   a4 * w3.x + a5 * w3.y + a6 * w3.z + a7 * w3.w;
#pragma unroll
        for (int off = 1; off <= 4; off <<= 1) {
            p0 += __shfl_xor(p0, off, 64);
            p1 += __shfl_xor(p1, off, 64);
        }
        if ((lane & 15) == 0) {
            out[(long)node * 2 + 0] = fmaxf(p0 + postb[0], 0.f);
            out[(long)node * 2 + 1] = fmaxf(p1 + postb[1], 0.f);
        }
    } else {
        if (g == 0) {
            float4 r0v; r0v.x = a0; r0v.y = a1; r0v.z = a2; r0v.w = a3;
            float4 r1v; r1v.x = a4; r1v.y = a5; r1v.z = a6; r1v.w = a7;
            float* dst = a + (long)node * 64 + f8;
            *(float4*)dst = r0v;
            *(float4*)(dst + 4) = r1v;
        }
    }
}

extern "C" void kernel_launch(void* const* d_in, const int* in_sizes, int n_in,
                              void* d_out, int out_size, void* d_ws, size_t ws_size,
                              hipStream_t stream) {
    const float* x = (const float*)d_in[0];
    const int* esrc = (const int*)d_in[1];
    const int* edst = esrc + N_EDGES;
    const float* preW = (const float*)d_in[2];
    const float* preb = (const float*)d_in[3];
    const float* postW = (const float*)d_in[4];
    const float* postb = (const float*)d_in[5];
    const float* relW[3] = {(const float*)d_in[6], (const float*)d_in[9], (const float*)d_in[12]};
    const float* relb[3] = {(const float*)d_in[7], (const float*)d_in[10], (const float*)d_in[13]};
    const float* rootW[3] = {(const float*)d_in[8], (const float*)d_in[11], (const float*)d_in[14]};
    float* out = (float*)d_out;

    const size_t NF = (size_t)N_NODES * HID;
    char* p = (char*)d_ws;
    float* hA = (float*)p; p += NF * 4;
    float* hB = (float*)p; p += NF * 4;
    __half* mB = (__half*)p; p += NF * 2;
    p = (char*)(((size_t)p + 255) & ~(size_t)255);
    int* rowp = (int*)p; p += (size_t)(N_NODES + 1) * 4;
    p = (char*)(((size_t)p + 255) & ~(size_t)255);
    int* ssrc = (int*)p; p += (size_t)N_EDGES * 4;
    int* bcur = (int*)p; p += 512 * 4;
    // tmp (NBKT*CAP*4 = 9.6 MB) aliases mB (12.8 MB): CSR build finishes
    // before any gemmt writes mB.
    unsigned int* tmp = (unsigned int*)mB;

    // --- build CSR (by dst): fixed-cap bins -> per-bucket sort (self-scanned) ---
    hipMemsetAsync(bcur, 0, 512 * 4, stream);
    bucket_kernel<<<(N_EDGES + TILE - 1) / TILE, 512, 0, stream>>>(esrc, edst, bcur, tmp);
    passb_kernel<<<NBKT, 256, 0, stream>>>(tmp, bcur, rowp, ssrc);

    const int GEMM_BLOCKS = (N_NODES + 127) / 128;      // 782
    const int GATHER_BLOCKS = N_NODES / 16;             // 4 nodes/wave, 4 waves/block

    const float S1 = 1.0f / 64.0f, IS1 = 64.0f;  // layers 1-2 fp16 range scaling

    // layer 0 (pre fused): x -> mB, hB(aout); m values ~O(1), no scaling
    gemmt_kernel<1><<<GEMM_BLOCKS, 256, 0, stream>>>(x, preW, preb, relW[0], relb[0],
                                                     rootW[0], 1.0f, mB, hB);
    gather_kernel<0><<<GATHER_BLOCKS, 256, 0, stream>>>(mB, hB, rowp, ssrc, 1.0f,
                                                        nullptr, nullptr, nullptr);
    // layer 1: hB -> mB, hA(aout)
    gemmt_kernel<0><<<GEMM_BLOCKS, 256, 0, stream>>>(hB, nullptr, nullptr, relW[1], relb[1],
                                                     rootW[1], S1, mB, hA);
    gather_kernel<0><<<GATHER_BLOCKS, 256, 0, stream>>>(mB, hA, rowp, ssrc, IS1,
                                                        nullptr, nullptr, nullptr);
    // layer 2 + post: hA -> out
    gemmt_kernel<0><<<GEMM_BLOCKS, 256, 0, stream>>>(hA, nullptr, nullptr, relW[2], relb[2],
                                                     rootW[2], S1, mB, hB);
    gather_kernel<1><<<GATHER_BLOCKS, 256, 0, stream>>>(mB, hB, rowp, ssrc, IS1,
                                                        postW, postb, out);
}

// Round 15
// 311.791 us; speedup vs baseline: 1.0650x; 1.0393x over previous
//
#include <hip/hip_runtime.h>
#include <hip/hip_fp16.h>

#define N_NODES 100000
#define N_EDGES 1600000
#define HID 64

#define BSH 8                         // bucket = dst >> 8 (256 nodes per bucket)
#define NBKT ((N_NODES + 255) / 256)  // 391
#define CAP 6144                      // fixed tmp region per bucket (mean 4093, sd 64)
#define TILE 4096                     // edges per bucket_kernel block (32 KB LDS)

#define HSC 0.015625f                 // 1/64: fp16 range scaling for h/aout (exact pow2)
#define HSCI 64.0f

// Pass A: bin edges by dst-bucket into fixed-capacity bucket regions of tmp.
// bcur is a zero-initialized per-bucket counter (region base = b*CAP).
// packed tmp word: (dst & 255) << 17 | src   (src < 2^17)
__global__ void __launch_bounds__(512) bucket_kernel(const int* __restrict__ src,
                                                     const int* __restrict__ dst,
                                                     int* __restrict__ bcur,
                                                     unsigned int* __restrict__ tmp) {
    __shared__ unsigned long long ed[TILE];  // 32 KB staged (dst<<32 | src)
    __shared__ int cnt[NBKT], cnt2[NBKT], scnx[NBKT], gbase[NBKT];
    __shared__ int s[512];
    int tid = threadIdx.x;
    int bstart = blockIdx.x * TILE;
    int tcnt = N_EDGES - bstart;
    if (tcnt > TILE) tcnt = TILE;
    if (tcnt < 0) tcnt = 0;
    for (int b = tid; b < NBKT; b += 512) { cnt[b] = 0; cnt2[b] = 0; }
    __syncthreads();
    for (int i = tid; i < tcnt; i += 512) atomicAdd(&cnt[dst[bstart + i] >> BSH], 1);
    __syncthreads();
    s[tid] = (tid < NBKT) ? cnt[tid] : 0;
    __syncthreads();
    for (int off = 1; off < 512; off <<= 1) {
        int add = (tid >= off) ? s[tid - off] : 0;
        __syncthreads();
        s[tid] += add;
        __syncthreads();
    }
    if (tid < NBKT) {
        scnx[tid] = s[tid] - cnt[tid];
        gbase[tid] = tid * CAP + atomicAdd(&bcur[tid], cnt[tid]);
    }
    __syncthreads();
    for (int i = tid; i < tcnt; i += 512) {
        int e = bstart + i;
        int d = dst[e], sc = src[e];
        int b = d >> BSH;
        int pos = scnx[b] + atomicAdd(&cnt2[b], 1);
        ed[pos] = ((unsigned long long)(unsigned)d << 32) | (unsigned)sc;
    }
    __syncthreads();
    for (int i = tid; i < tcnt; i += 512) {
        unsigned long long v = ed[i];
        int d = (int)(v >> 32);
        unsigned sc = (unsigned)v;
        int b = d >> BSH;
        int idx = gbase[b] + (i - scnx[b]);
        if (idx < (b + 1) * CAP)  // statistically unreachable guard
            tmp[idx] = ((unsigned)(d & 255) << 17) | sc;
    }
}

// Pass B: per bucket. Computes its own global offset lo = sum_{b'<b} cnt[b']
// (fused scan), then node degrees in LDS, scan -> rowp, counting-sort scatter.
__global__ void __launch_bounds__(256) passb_kernel(const unsigned int* __restrict__ tmp,
                                                    const int* __restrict__ bcur,
                                                    int* __restrict__ rowp,
                                                    int* __restrict__ ssrc) {
    __shared__ int red[256];
    __shared__ int cnt[256], s[256], cur[256];
    int tid = threadIdx.x;
    int b = blockIdx.x;
    int acc = 0;
    for (int i = tid; i < b; i += 256) {
        int c = bcur[i];
        if (c > CAP) c = CAP;
        acc += c;
    }
    red[tid] = acc;
    __syncthreads();
    for (int off = 128; off >= 1; off >>= 1) {
        if (tid < off) red[tid] += red[tid + off];
        __syncthreads();
    }
    int lo = red[0];
    int ne = bcur[b];
    if (ne > CAP) ne = CAP;
    if (b == NBKT - 1 && tid == 0) rowp[N_NODES] = lo + ne;
    int lo_t = b * CAP;
    cnt[tid] = 0;
    __syncthreads();
    for (int i = tid; i < ne; i += 256) atomicAdd(&cnt[tmp[lo_t + i] >> 17], 1);
    __syncthreads();
    int v = cnt[tid];
    s[tid] = v;
    __syncthreads();
    for (int off = 1; off < 256; off <<= 1) {
        int a = (tid >= off) ? s[tid - off] : 0;
        __syncthreads();
        s[tid] += a;
        __syncthreads();
    }
    int excl = lo + s[tid] - v;
    int node = (b << BSH) + tid;
    if (node < N_NODES) rowp[node] = excl;
    cur[tid] = excl;
    __syncthreads();
    for (int i = tid; i < ne; i += 256) {
        unsigned u = tmp[lo_t + i];
        int pos = atomicAdd(&cur[u >> 17], 1);
        ssrc[pos] = (int)(u & 0x1FFFF);
    }
}

// Register-tiled dual GEMM: m = fp16(mscale*(h @ relW.T)), aout = fp16(HSC*(h @ rootW.T + relb)).
// All scales exact powers of 2. h input (PRE=0) is fp16 scaled by HSC; staging
// converts and multiplies by HSCI (exact). Block tile: 128 nodes x 128 outputs.
// PRE=1: input is x[N,3] fp32; h tile computed in staging as relu(x@preW+preb).
// NOTE (R11 bug): xs staging MUST loop t = tid..384 step 256 — partial-coverage
// `if (tid < 384)` left xs[256..383] as uninitialized LDS -> nondeterminism.
template <int PRE>
__global__ void __launch_bounds__(256) gemmt_kernel(const void* __restrict__ hx,
                                                    const float* __restrict__ preW,
                                                    const float* __restrict__ preb,
                                                    const float* __restrict__ relW,
                                                    const float* __restrict__ relb,
                                                    const float* __restrict__ rootW,
                                                    float mscale,
                                                    __half* __restrict__ m,
                                                    __half* __restrict__ aout) {
    __shared__ float hs[128 * 68];
    __shared__ float ws[128 * 68];
    __shared__ float xs[PRE ? 384 : 1];
    __shared__ float pw[PRE ? 192 : 1];
    __shared__ float pbs[PRE ? 64 : 1];
    int tid = threadIdx.x;
    int i0 = blockIdx.x * 128;
    // stage weights (always)
    for (int c = 0; c < 8; c++) {
        int f = tid + c * 256;  // float4 index over 128x64
        int j = f >> 4, c4 = (f & 15) << 2;
        float4 wv = (j < 64) ? *(const float4*)&relW[j * 64 + c4]
                             : *(const float4*)&rootW[(j - 64) * 64 + c4];
        *(float4*)&ws[j * 68 + c4] = wv;
    }
    if (PRE) {
        const float* x = (const float*)hx;
        if (tid < 192) pw[tid] = preW[tid];
        if (tid < 64) pbs[tid] = preb[tid];
        for (int t = tid; t < 384; t += 256) {  // FULL coverage of xs[0..383]
            int gi = i0 * 3 + t;
            xs[t] = (gi < N_NODES * 3) ? x[gi] : 0.f;
        }
        __syncthreads();
        for (int c = 0; c < 32; c++) {
            int e = c * 256 + tid;
            int row = e >> 6, col = e & 63;
            float v = pbs[col];
            v = fmaf(xs[row * 3 + 0], pw[col * 3 + 0], v);
            v = fmaf(xs[row * 3 + 1], pw[col * 3 + 1], v);
            v = fmaf(xs[row * 3 + 2], pw[col * 3 + 2], v);
            hs[row * 68 + col] = fmaxf(v, 0.f);
        }
    } else {
        const __half* h = (const __half*)hx;
        for (int c = 0; c < 4; c++) {
            int f = tid + c * 256;  // half8 chunk index, 1024 total
            int row = f >> 3, c8 = (f & 7) << 3;
            uint4 hv = {0u, 0u, 0u, 0u};
            if (i0 + row < N_NODES) hv = *(const uint4*)(h + (long)(i0 + row) * 64 + c8);
            const __half2* hp = (const __half2*)&hv;
            float2 f0 = __half22float2(hp[0]), f1 = __half22float2(hp[1]);
            float2 f2 = __half22float2(hp[2]), f3 = __half22float2(hp[3]);
            float* dstp = &hs[row * 68 + c8];
            dstp[0] = f0.x * HSCI; dstp[1] = f0.y * HSCI;
            dstp[2] = f1.x * HSCI; dstp[3] = f1.y * HSCI;
            dstp[4] = f2.x * HSCI; dstp[5] = f2.y * HSCI;
            dstp[6] = f3.x * HSCI; dstp[7] = f3.y * HSCI;
        }
    }
    int ig = tid >> 4;   // node group 0..15, nodes ig+16n
    int jg = tid & 15;   // out group 0..15,  outs  jg+16m
    float rb[4];
#pragma unroll
    for (int t = 0; t < 4; t++) rb[t] = relb[jg + 16 * t];
    float acc[8][8];
#pragma unroll
    for (int n = 0; n < 8; n++)
#pragma unroll
        for (int mm = 0; mm < 8; mm++) acc[n][mm] = 0.f;
    __syncthreads();

    for (int kk = 0; kk < 64; kk += 4) {
        float4 av[8], bv[8];
#pragma unroll
        for (int n = 0; n < 8; n++) av[n] = *(const float4*)&hs[(ig + 16 * n) * 68 + kk];
#pragma unroll
        for (int mm = 0; mm < 8; mm++) bv[mm] = *(const float4*)&ws[(jg + 16 * mm) * 68 + kk];
#pragma unroll
        for (int n = 0; n < 8; n++)
#pragma unroll
            for (int mm = 0; mm < 8; mm++) {
                acc[n][mm] = fmaf(av[n].x, bv[mm].x, acc[n][mm]);
                acc[n][mm] = fmaf(av[n].y, bv[mm].y, acc[n][mm]);
                acc[n][mm] = fmaf(av[n].z, bv[mm].z, acc[n][mm]);
                acc[n][mm] = fmaf(av[n].w, bv[mm].w, acc[n][mm]);
            }
    }
#pragma unroll
    for (int n = 0; n < 8; n++) {
        int node = i0 + ig + 16 * n;
        if (node >= N_NODES) continue;
#pragma unroll
        for (int mm = 0; mm < 4; mm++)
            m[(long)node * 64 + jg + 16 * mm] = __float2half(acc[n][mm] * mscale);
#pragma unroll
        for (int mm = 4; mm < 8; mm++)
            aout[(long)node * 64 + jg + 16 * (mm - 4)] =
                __float2half((acc[n][mm] + rb[mm - 4]) * HSC);
    }
}

// fp16-m gather, 4 nodes per wave: n = lane>>4 (node quarter), g = (lane>>3)&1
// (edge subgroup), f8 = (lane&7)*8 (feature oct). Per-lane direct index loads,
// fp32 accumulate; root-term (fp16, HSC-scaled) load hoisted; rowp scalarized.
// 4-pair unroll max (deeper regressed via VGPR/occupancy — R13).
// aggscale = 1/mscale (pow2, exact); root term unscaled by HSCI; non-final
// h output stored fp16 scaled by HSC.
template <int FINAL>
__global__ void gather_kernel(const __half* __restrict__ m, __half* __restrict__ a,
                              const int* __restrict__ rowp, const int* __restrict__ ssrc,
                              float aggscale,
                              const float* __restrict__ postW, const float* __restrict__ postb,
                              float* __restrict__ out) {
    int lane = threadIdx.x & 63;
    int wv = (blockIdx.x * blockDim.x + threadIdx.x) >> 6;
    int pb = wv * 4;
    if (pb >= N_NODES) return;
    int n = lane >> 4;          // node quarter 0..3
    int g = (lane >> 3) & 1;    // edge subgroup 0/1
    int f8 = (lane & 7) << 3;   // feature base 0,8,...,56
    pb = __builtin_amdgcn_readfirstlane(pb);
    int q0 = rowp[pb], q1 = rowp[pb + 1], q2 = rowp[pb + 2];
    int q3 = rowp[pb + 3], q4 = rowp[pb + 4];
    int node = pb + n;
    int r0 = (n == 0) ? q0 : (n == 1) ? q1 : (n == 2) ? q2 : q3;
    int r1 = (n == 0) ? q1 : (n == 1) ? q2 : (n == 2) ? q3 : q4;
    int nedge = r1 - r0;
    // hoisted root-term load (fp16, overlaps the edge loop)
    uint4 av = *(const uint4*)(a + (long)node * 64 + f8);
    float a0 = 0.f, a1 = 0.f, a2 = 0.f, a3 = 0.f, a4 = 0.f, a5 = 0.f, a6 = 0.f, a7 = 0.f;
#define ACC8(u)                                                         \
    {                                                                   \
        float2 f_;                                                      \
        f_ = __half22float2(*(__half2*)&(u).x); a0 += f_.x; a1 += f_.y; \
        f_ = __half22float2(*(__half2*)&(u).y); a2 += f_.x; a3 += f_.y; \
        f_ = __half22float2(*(__half2*)&(u).z); a4 += f_.x; a5 += f_.y; \
        f_ = __half22float2(*(__half2*)&(u).w); a6 += f_.x; a7 += f_.y; \
    }
    int ns = nedge >> 1;        // pairs of edges (2 subgroups cover 2 edges/iter)
    int q = 0;
    for (; q + 4 <= ns; q += 4) {
        int b0 = r0 + q * 2 + g;
        int i0 = ssrc[b0];
        int i1 = ssrc[b0 + 2];
        int i2 = ssrc[b0 + 4];
        int i3 = ssrc[b0 + 6];
        uint4 u0 = *(const uint4*)(m + (long)i0 * 64 + f8);
        uint4 u1 = *(const uint4*)(m + (long)i1 * 64 + f8);
        uint4 u2 = *(const uint4*)(m + (long)i2 * 64 + f8);
        uint4 u3 = *(const uint4*)(m + (long)i3 * 64 + f8);
        ACC8(u0); ACC8(u1); ACC8(u2); ACC8(u3);
    }
    if (q + 2 <= ns) {
        int b0 = r0 + q * 2 + g;
        int i0 = ssrc[b0];
        int i1 = ssrc[b0 + 2];
        uint4 u0 = *(const uint4*)(m + (long)i0 * 64 + f8);
        uint4 u1 = *(const uint4*)(m + (long)i1 * 64 + f8);
        ACC8(u0); ACC8(u1);
        q += 2;
    }
    if (q < ns) {
        int i0 = ssrc[r0 + q * 2 + g];
        uint4 u0 = *(const uint4*)(m + (long)i0 * 64 + f8);
        ACC8(u0);
    }
    if ((nedge & 1) && g == 0) {
        int i0 = ssrc[r0 + ns * 2];
        uint4 u0 = *(const uint4*)(m + (long)i0 * 64 + f8);
        ACC8(u0);
    }
#undef ACC8
    // reduce across the 2 edge subgroups (stays within each 16-lane node group)
    a0 += __shfl_xor(a0, 8, 64); a1 += __shfl_xor(a1, 8, 64);
    a2 += __shfl_xor(a2, 8, 64); a3 += __shfl_xor(a3, 8, 64);
    a4 += __shfl_xor(a4, 8, 64); a5 += __shfl_xor(a5, 8, 64);
    a6 += __shfl_xor(a6, 8, 64); a7 += __shfl_xor(a7, 8, 64);
    // undo fp16 range scalings (exact powers of 2)
    a0 *= aggscale; a1 *= aggscale; a2 *= aggscale; a3 *= aggscale;
    a4 *= aggscale; a5 *= aggscale; a6 *= aggscale; a7 *= aggscale;
    const __half2* ap = (const __half2*)&av;
    float2 o0 = __half22float2(ap[0]), o1 = __half22float2(ap[1]);
    float2 o2 = __half22float2(ap[2]), o3 = __half22float2(ap[3]);
    a0 = fmaxf(fmaf(o0.x, HSCI, a0), 0.f); a1 = fmaxf(fmaf(o0.y, HSCI, a1), 0.f);
    a2 = fmaxf(fmaf(o1.x, HSCI, a2), 0.f); a3 = fmaxf(fmaf(o1.y, HSCI, a3), 0.f);
    a4 = fmaxf(fmaf(o2.x, HSCI, a4), 0.f); a5 = fmaxf(fmaf(o2.y, HSCI, a5), 0.f);
    a6 = fmaxf(fmaf(o3.x, HSCI, a6), 0.f); a7 = fmaxf(fmaf(o3.y, HSCI, a7), 0.f);
    if (FINAL) {
        float4 w0 = *(const float4*)(postW + f8);
        float4 w1 = *(const float4*)(postW + f8 + 4);
        float4 w2 = *(const float4*)(postW + 64 + f8);
        float4 w3 = *(const float4*)(postW + 64 + f8 + 4);
        float p0 = a0 * w0.x + a1 * w0.y + a2 * w0.z + a3 * w0.w +
                   a4 * w1.x + a5 * w1.y + a6 * w1.z + a7 * w1.w;
        float p1 = a0 * w2.x + a1 * w2.y + a2 * w2.z + a3 * w2.w +
                   a4 * w3.x + a5 * w3.y + a6 * w3.z + a7 * w3.w;
#pragma unroll
        for (int off = 1; off <= 4; off <<= 1) {
            p0 += __shfl_xor(p0, off, 64);
            p1 += __shfl_xor(p1, off, 64);
        }
        if ((lane & 15) == 0) {
            out[(long)node * 2 + 0] = fmaxf(p0 + postb[0], 0.f);
            out[(long)node * 2 + 1] = fmaxf(p1 + postb[1], 0.f);
        }
    } else {
        if (g == 0) {
            uint4 st;
            __half2* sp = (__half2*)&st;
            sp[0] = __floats2half2_rn(a0 * HSC, a1 * HSC);
            sp[1] = __floats2half2_rn(a2 * HSC, a3 * HSC);
            sp[2] = __floats2half2_rn(a4 * HSC, a5 * HSC);
            sp[3] = __floats2half2_rn(a6 * HSC, a7 * HSC);
            *(uint4*)(a + (long)node * 64 + f8) = st;
        }
    }
}

extern "C" void kernel_launch(void* const* d_in, const int* in_sizes, int n_in,
                              void* d_out, int out_size, void* d_ws, size_t ws_size,
                              hipStream_t stream) {
    const float* x = (const float*)d_in[0];
    const int* esrc = (const int*)d_in[1];
    const int* edst = esrc + N_EDGES;
    const float* preW = (const float*)d_in[2];
    const float* preb = (const float*)d_in[3];
    const float* postW = (const float*)d_in[4];
    const float* postb = (const float*)d_in[5];
    const float* relW[3] = {(const float*)d_in[6], (const float*)d_in[9], (const float*)d_in[12]};
    const float* relb[3] = {(const float*)d_in[7], (const float*)d_in[10], (const float*)d_in[13]};
    const float* rootW[3] = {(const float*)d_in[8], (const float*)d_in[11], (const float*)d_in[14]};
    float* out = (float*)d_out;

    const size_t NF = (size_t)N_NODES * HID;
    char* p = (char*)d_ws;
    __half* hA = (__half*)p; p += NF * 2;
    __half* hB = (__half*)p; p += NF * 2;
    __half* mB = (__half*)p; p += NF * 2;
    p = (char*)(((size_t)p + 255) & ~(size_t)255);
    int* rowp = (int*)p; p += (size_t)(N_NODES + 1) * 4;
    p = (char*)(((size_t)p + 255) & ~(size_t)255);
    int* ssrc = (int*)p; p += (size_t)N_EDGES * 4;
    int* bcur = (int*)p; p += 512 * 4;
    // tmp (NBKT*CAP*4 = 9.6 MB) aliases hA+hB (12.8 MB): CSR build finishes
    // before the first gemmt writes either.
    unsigned int* tmp = (unsigned int*)hA;

    // --- build CSR (by dst): fixed-cap bins -> per-bucket sort (self-scanned) ---
    hipMemsetAsync(bcur, 0, 512 * 4, stream);
    bucket_kernel<<<(N_EDGES + TILE - 1) / TILE, 512, 0, stream>>>(esrc, edst, bcur, tmp);
    passb_kernel<<<NBKT, 256, 0, stream>>>(tmp, bcur, rowp, ssrc);

    const int GEMM_BLOCKS = (N_NODES + 127) / 128;      // 782
    const int GATHER_BLOCKS = N_NODES / 16;             // 4 nodes/wave, 4 waves/block

    const float S1 = 1.0f / 64.0f, IS1 = 64.0f;  // layers 1-2 m fp16 range scaling

    // layer 0 (pre fused): x -> mB, hB(aout); m values ~O(1), no m scaling
    gemmt_kernel<1><<<GEMM_BLOCKS, 256, 0, stream>>>(x, preW, preb, relW[0], relb[0],
                                                     rootW[0], 1.0f, mB, hB);
    gather_kernel<0><<<GATHER_BLOCKS, 256, 0, stream>>>(mB, hB, rowp, ssrc, 1.0f,
                                                        nullptr, nullptr, nullptr);
    // layer 1: hB -> mB, hA(aout)
    gemmt_kernel<0><<<GEMM_BLOCKS, 256, 0, stream>>>(hB, nullptr, nullptr, relW[1], relb[1],
                                                     rootW[1], S1, mB, hA);
    gather_kernel<0><<<GATHER_BLOCKS, 256, 0, stream>>>(mB, hA, rowp, ssrc, IS1,
                                                        nullptr, nullptr, nullptr);
    // layer 2 + post: hA -> out
    gemmt_kernel<0><<<GEMM_BLOCKS, 256, 0, stream>>>(hA, nullptr, nullptr, relW[2], relb[2],
                                                     rootW[2], S1, mB, hB);
    gather_kernel<1><<<GATHER_BLOCKS, 256, 0, stream>>>(mB, hB, rowp, ssrc, IS1,
                                                        postW, postb, out);
}